// Round 2
// baseline (2129.194 us; speedup 1.0000x reference)
//
#include <hip/hip_runtime.h>

// Fused Swin-style window attention for MI355X (gfx950), v3.
// One block (256 thr / 4 waves) per 8x8 window. FP16 MFMA (16x16x32), fp32 acc.
// v3: register-only fragment transposition. Q/K computed transposed
// (mfma(W,XN): tokens on l16), V normal (features on l16); Q/K/V/P fragments
// built via ds_bpermute quad-redistribution (8 bperm + 4 cndmask per frag),
// wave-local, conflict-free. LDS = XN buffer only (35.8 KB) -> 3 blocks/CU
// (12 waves, was 8). Barriers 7 -> 4. Phase-0 packs c-pairs into half2 writes.

typedef _Float16 half8  __attribute__((ext_vector_type(8)));
typedef _Float16 half2v __attribute__((ext_vector_type(2)));
typedef float    f32x4  __attribute__((ext_vector_type(4)));

#define XN_STR 264
#define XN_SZ  (64 * XN_STR)   // 16896 halfs = 33792 B

// XN addr: [row 0..63][c 0..255], 16B-chunk XOR swizzle keyed by row>>3,
// pad +8 rotates banks by 4 per row (row-parallel reads ~2-way).
__device__ __forceinline__ int xn_idx(int row, int c) {
    return row * XN_STR + (((c >> 3) ^ (row >> 3)) << 3) + (c & 7);
}

__device__ __forceinline__ int pk2(float a, float b) {
    half2v h = { (_Float16)a, (_Float16)b };
    return __builtin_bit_cast(int, h);
}

// pull one fragment word: target needs pk[I0] (quad<2) or pk[I1] (quad>=2),
// from src lane encoded in idx.
__device__ __forceinline__ int qsel(bool hi, int idx, int lo_r, int hi_r) {
    int a = __builtin_amdgcn_ds_bpermute(idx, lo_r);
    int b = __builtin_amdgcn_ds_bpermute(idx, hi_r);
    return hi ? b : a;
}

__device__ __forceinline__ half8 frag4(int w0, int w1, int w2, int w3) {
    int4 t = { w0, w1, w2, w3 };
    return __builtin_bit_cast(half8, t);
}

__global__ void __launch_bounds__(256)
prep_weights_f16(const float* __restrict__ w_in, const float* __restrict__ w_out,
                 _Float16* __restrict__ wh) {
    int i = blockIdx.x * 256 + threadIdx.x;
    if (i < 196608)      wh[i] = (_Float16)w_in[i];
    else if (i < 262144) wh[i] = (_Float16)w_out[i - 196608];
}

__global__ void __launch_bounds__(256, 3)
win_attn_fused(const float* __restrict__ x, const float* __restrict__ gamma,
               const float* __restrict__ beta, const float* __restrict__ b_in,
               const float* __restrict__ b_out,
               const _Float16* __restrict__ w_in_h,
               const _Float16* __restrict__ w_out_h,
               float* __restrict__ out)
{
    __shared__ __align__(16) _Float16 sm[XN_SZ];
    __shared__ float s_gb[512];

    const int tid  = threadIdx.x;
    // XCD-bijective remap (4096 blocks, 8 XCDs)
    const int bidr = blockIdx.x;
    const int wid  = (bidr & 7) * 512 + (bidr >> 3);
    const int b    = wid >> 8;
    const int whi  = (wid >> 4) & 15;
    const int wwi  = wid & 15;
    const int h0 = whi * 8, w0 = wwi * 8;

    s_gb[tid]       = gamma[tid];
    s_gb[256 + tid] = beta[tid];

    const int wv   = tid >> 6;
    const int lane = tid & 63;
    const int quad = lane >> 4;
    const int l16  = lane & 15;

    // ---- phase 0: gather window -> XN [tok][c] fp16 (swizzled, half2 writes) ----
    {
        const int th = lane & 7;
        const int qq = (lane >> 3) & 1;
        const int cp = lane >> 4;           // c-pair slot 0..3
        const int rowb = th * 8 + qq * 4;   // (rowb+r)>>3 == th for r=0..3
        const float* xb = x + (((size_t)b * 256) * 128 + h0) * 128 + w0;
#pragma unroll
        for (int it = 0; it < 8; ++it) {
            int c0 = it * 32 + wv * 8 + cp * 2;          // even; c0>>3 = it*4+wv
            float4 v0 = *(const float4*)(xb + ((size_t)c0 * 128 + th) * 128 + qq * 4);
            float4 v1 = *(const float4*)(xb + ((size_t)(c0 + 1) * 128 + th) * 128 + qq * 4);
            int base = rowb * XN_STR + (((c0 >> 3) ^ th) << 3) + (c0 & 7);
            *(half2v*)&sm[base]              = half2v{ (_Float16)v0.x, (_Float16)v1.x };
            *(half2v*)&sm[base + XN_STR]     = half2v{ (_Float16)v0.y, (_Float16)v1.y };
            *(half2v*)&sm[base + 2 * XN_STR] = half2v{ (_Float16)v0.z, (_Float16)v1.z };
            *(half2v*)&sm[base + 3 * XN_STR] = half2v{ (_Float16)v0.w, (_Float16)v1.w };
        }
    }
    __syncthreads();

    // ---- LayerNorm in place (4 threads per token, butterfly stats) ----
    {
        const int tok = tid >> 2, cq = tid & 3;
        float sum = 0.f, ss = 0.f;
        half8 hv[8];
#pragma unroll
        for (int k2 = 0; k2 < 8; ++k2) {
            hv[k2] = *(const half8*)&sm[xn_idx(tok, cq * 64 + k2 * 8)];
#pragma unroll
            for (int j = 0; j < 8; ++j) { float f = (float)hv[k2][j]; sum += f; ss += f * f; }
        }
        sum += __shfl_xor(sum, 1); ss += __shfl_xor(ss, 1);
        sum += __shfl_xor(sum, 2); ss += __shfl_xor(ss, 2);
        float mu   = sum * (1.f / 256.f);
        float var  = ss * (1.f / 256.f) - mu * mu;
        float rstd = rsqrtf(var + 1e-5f);
#pragma unroll
        for (int k2 = 0; k2 < 8; ++k2) {
            int c0 = cq * 64 + k2 * 8;
            half8 o;
#pragma unroll
            for (int j = 0; j < 8; ++j)
                o[j] = (_Float16)(((float)hv[k2][j] - mu) * rstd * s_gb[c0 + j] + s_gb[256 + c0 + j]);
            *(half8*)&sm[xn_idx(tok, c0)] = o;
        }
    }
    __syncthreads();

    const f32x4 zero4 = {0.f, 0.f, 0.f, 0.f};
    // bpermute indices: src lane = 32*(quad&1) + 16*g + l16 (g=0: idxA, g=1: idxB)
    const int idxA = ((lane & 16) << 3) | ((lane & 15) << 2);
    const int idxB = idxA + 64;
    const bool hi2 = (lane & 32) != 0;     // quad>>1: selects I-pair member

    // 64x64 GEMM vs w_in cols [p*256 + wv*64, +64).
    // xn_as_A=false: acc[ft][tt] = W x XN (features on rows, tokens on l16)
    // xn_as_A=true:  acc[tt][ft] = XN x W (tokens on rows, features on l16)
    auto gemm_pass = [&](const int p, const bool xn_as_A, f32x4 (&acc)[4][4]) {
#pragma unroll
        for (int i = 0; i < 4; ++i)
#pragma unroll
            for (int j = 0; j < 4; ++j) acc[i][j] = zero4;
        const _Float16* wb = w_in_h + ((size_t)(p * 256 + wv * 64 + l16)) * 256 + quad * 8;
#pragma unroll
        for (int kb = 0; kb < 8; ++kb) {
            half8 wf[4], bx[4];
#pragma unroll
            for (int i = 0; i < 4; ++i)
                wf[i] = *(const half8*)(wb + (size_t)i * 16 * 256 + kb * 32);
#pragma unroll
            for (int j = 0; j < 4; ++j)
                bx[j] = *(const half8*)&sm[xn_idx(j * 16 + l16, kb * 32 + quad * 8)];
            if (xn_as_A) {
#pragma unroll
                for (int i = 0; i < 4; ++i)
#pragma unroll
                    for (int j = 0; j < 4; ++j)
                        acc[i][j] = __builtin_amdgcn_mfma_f32_16x16x32_f16(bx[i], wf[j], acc[i][j], 0, 0, 0);
            } else {
#pragma unroll
                for (int i = 0; i < 4; ++i)
#pragma unroll
                    for (int j = 0; j < 4; ++j)
                        acc[i][j] = __builtin_amdgcn_mfma_f32_16x16x32_f16(wf[i], bx[j], acc[i][j], 0, 0, 0);
            }
        }
    };

    half8 qfrag[2][4], kfrag[2][4], vfrag[2][2][2];

    // ---- pass Q (transposed): acc[featT][tokT] -> qfrag[hh][nt] ----
    {
        f32x4 acc[4][4];
        gemm_pass(0, false, acc);
#pragma unroll
        for (int mt = 0; mt < 4; ++mt) {
            f32x4 bq = *(const f32x4*)&b_in[0 * 256 + wv * 64 + mt * 16 + quad * 4];
#pragma unroll
            for (int nt = 0; nt < 4; ++nt) acc[mt][nt] += bq;
        }
        int pkq[4][4][2];
#pragma unroll
        for (int mt = 0; mt < 4; ++mt)
#pragma unroll
            for (int nt = 0; nt < 4; ++nt) {
                pkq[mt][nt][0] = pk2(acc[mt][nt][0], acc[mt][nt][1]);
                pkq[mt][nt][1] = pk2(acc[mt][nt][2], acc[mt][nt][3]);
            }
#pragma unroll
        for (int hh = 0; hh < 2; ++hh)
#pragma unroll
            for (int nt = 0; nt < 4; ++nt)
                qfrag[hh][nt] = frag4(
                    qsel(hi2, idxA, pkq[2*hh][nt][0], pkq[2*hh+1][nt][0]),
                    qsel(hi2, idxA, pkq[2*hh][nt][1], pkq[2*hh+1][nt][1]),
                    qsel(hi2, idxB, pkq[2*hh][nt][0], pkq[2*hh+1][nt][0]),
                    qsel(hi2, idxB, pkq[2*hh][nt][1], pkq[2*hh+1][nt][1]));
    }

    // ---- pass K (transposed) -> kfrag[hh][mt] ----
    {
        f32x4 acc[4][4];
        gemm_pass(1, false, acc);
#pragma unroll
        for (int mt = 0; mt < 4; ++mt) {
            f32x4 bk = *(const f32x4*)&b_in[1 * 256 + wv * 64 + mt * 16 + quad * 4];
#pragma unroll
            for (int nt = 0; nt < 4; ++nt) acc[mt][nt] += bk;
        }
        int pkk[4][4][2];
#pragma unroll
        for (int mt = 0; mt < 4; ++mt)
#pragma unroll
            for (int nt = 0; nt < 4; ++nt) {
                pkk[mt][nt][0] = pk2(acc[mt][nt][0], acc[mt][nt][1]);
                pkk[mt][nt][1] = pk2(acc[mt][nt][2], acc[mt][nt][3]);
            }
#pragma unroll
        for (int hh = 0; hh < 2; ++hh)
#pragma unroll
            for (int nt = 0; nt < 4; ++nt)
                kfrag[hh][nt] = frag4(
                    qsel(hi2, idxA, pkk[2*hh][nt][0], pkk[2*hh+1][nt][0]),
                    qsel(hi2, idxA, pkk[2*hh][nt][1], pkk[2*hh+1][nt][1]),
                    qsel(hi2, idxB, pkk[2*hh][nt][0], pkk[2*hh+1][nt][0]),
                    qsel(hi2, idxB, pkk[2*hh][nt][1], pkk[2*hh+1][nt][1]));
    }

    // ---- pass V (normal): acc[tokT][featT] -> vfrag[hh][mtv][kb] ----
    {
        f32x4 acc[4][4];
        gemm_pass(2, true, acc);
#pragma unroll
        for (int nt = 0; nt < 4; ++nt) {
            float bv = b_in[2 * 256 + wv * 64 + nt * 16 + l16];
            f32x4 bvv = { bv, bv, bv, bv };
#pragma unroll
            for (int mt = 0; mt < 4; ++mt) acc[mt][nt] += bvv;
        }
        int pkv[4][4][2];
#pragma unroll
        for (int mt = 0; mt < 4; ++mt)
#pragma unroll
            for (int nt = 0; nt < 4; ++nt) {
                pkv[mt][nt][0] = pk2(acc[mt][nt][0], acc[mt][nt][1]);
                pkv[mt][nt][1] = pk2(acc[mt][nt][2], acc[mt][nt][3]);
            }
        __syncthreads();   // all waves done reading XN -> region reusable as obuf
#pragma unroll
        for (int hh = 0; hh < 2; ++hh)
#pragma unroll
            for (int mtv = 0; mtv < 2; ++mtv)
#pragma unroll
                for (int kb = 0; kb < 2; ++kb)
                    vfrag[hh][mtv][kb] = frag4(
                        qsel(hi2, idxA, pkv[2*kb][2*hh+mtv][0], pkv[2*kb+1][2*hh+mtv][0]),
                        qsel(hi2, idxA, pkv[2*kb][2*hh+mtv][1], pkv[2*kb+1][2*hh+mtv][1]),
                        qsel(hi2, idxB, pkv[2*kb][2*hh+mtv][0], pkv[2*kb+1][2*hh+mtv][0]),
                        qsel(hi2, idxB, pkv[2*kb][2*hh+mtv][1], pkv[2*kb+1][2*hh+mtv][1]));
    }

    // ---- attention: wave wv owns heads 2wv,2wv+1; streamed per q-tile ----
    const float SC = 0.17677669529663687f * 1.4426950408889634f;
#pragma unroll
    for (int hh = 0; hh < 2; ++hh) {
        f32x4 oacc[2][4];
#pragma unroll
        for (int mtv = 0; mtv < 2; ++mtv)
#pragma unroll
            for (int nt = 0; nt < 4; ++nt) oacc[mtv][nt] = zero4;

#pragma unroll
        for (int nt = 0; nt < 4; ++nt) {
            // scores^T tile: rows = all 64 k-tokens, cols = q-tokens nt*16..+16
            f32x4 s4[4];
#pragma unroll
            for (int mt = 0; mt < 4; ++mt)
                s4[mt] = __builtin_amdgcn_mfma_f32_16x16x32_f16(kfrag[hh][mt], qfrag[hh][nt], zero4, 0, 0, 0);
            float mx = -3.0e38f;
#pragma unroll
            for (int mt = 0; mt < 4; ++mt)
#pragma unroll
                for (int r = 0; r < 4; ++r) mx = fmaxf(mx, s4[mt][r]);
            mx = fmaxf(mx, __shfl_xor(mx, 16));
            mx = fmaxf(mx, __shfl_xor(mx, 32));
            float sum = 0.f;
#pragma unroll
            for (int mt = 0; mt < 4; ++mt)
#pragma unroll
                for (int r = 0; r < 4; ++r) {
                    float e = exp2f((s4[mt][r] - mx) * SC);
                    s4[mt][r] = e; sum += e;
                }
            sum += __shfl_xor(sum, 16);
            sum += __shfl_xor(sum, 32);
            float rs = 1.f / sum;
            int pks[4][2];
#pragma unroll
            for (int mt = 0; mt < 4; ++mt) {
                pks[mt][0] = pk2(s4[mt][0] * rs, s4[mt][1] * rs);
                pks[mt][1] = pk2(s4[mt][2] * rs, s4[mt][3] * rs);
            }
#pragma unroll
            for (int kb = 0; kb < 2; ++kb) {
                half8 pf = frag4(
                    qsel(hi2, idxA, pks[2*kb][0], pks[2*kb+1][0]),
                    qsel(hi2, idxA, pks[2*kb][1], pks[2*kb+1][1]),
                    qsel(hi2, idxB, pks[2*kb][0], pks[2*kb+1][0]),
                    qsel(hi2, idxB, pks[2*kb][1], pks[2*kb+1][1]));
#pragma unroll
                for (int mtv = 0; mtv < 2; ++mtv)
                    oacc[mtv][nt] = __builtin_amdgcn_mfma_f32_16x16x32_f16(vfrag[hh][mtv][kb], pf, oacc[mtv][nt], 0, 0, 0);
            }
        }
        // normalized attn output -> obuf[tok][c] (XN region, swizzled)
#pragma unroll
        for (int mtv = 0; mtv < 2; ++mtv)
#pragma unroll
            for (int nt = 0; nt < 4; ++nt) {
                int tok = nt * 16 + l16;
                int c0  = (2 * wv + hh) * 32 + mtv * 16 + quad * 4;
                int a0  = xn_idx(tok, c0);
                *(half2v*)&sm[a0]     = half2v{ (_Float16)oacc[mtv][nt][0], (_Float16)oacc[mtv][nt][1] };
                *(half2v*)&sm[a0 + 2] = half2v{ (_Float16)oacc[mtv][nt][2], (_Float16)oacc[mtv][nt][3] };
            }
    }
    __syncthreads();

    // ---- phase 3: y^T = w_out . obuf^T (each wave owns 64 w_out rows) ----
    f32x4 pacc[4][4];
#pragma unroll
    for (int mt = 0; mt < 4; ++mt)
#pragma unroll
        for (int nt = 0; nt < 4; ++nt) pacc[mt][nt] = zero4;
    const _Float16* wor = w_out_h + (size_t)(64 * wv + l16) * 256 + quad * 8;
#pragma unroll
    for (int kb = 0; kb < 256; kb += 32) {
        half8 aw[4], bo[4];
#pragma unroll
        for (int mt = 0; mt < 4; ++mt) aw[mt] = *(const half8*)(wor + mt * 16 * 256 + kb);
#pragma unroll
        for (int nt = 0; nt < 4; ++nt)
            bo[nt] = *(const half8*)&sm[xn_idx(nt * 16 + l16, kb + quad * 8)];
#pragma unroll
        for (int mt = 0; mt < 4; ++mt)
#pragma unroll
            for (int nt = 0; nt < 4; ++nt)
                pacc[mt][nt] = __builtin_amdgcn_mfma_f32_16x16x32_f16(aw[mt], bo[nt], pacc[mt][nt], 0, 0, 0);
    }

    // ---- epilogue: bias + scatter to (B,C,H,W) fp32 ----
    float* ob = out + (((size_t)b * 256) * 128 + h0) * 128 + w0;
#pragma unroll
    for (int mt = 0; mt < 4; ++mt) {
#pragma unroll
        for (int r = 0; r < 4; ++r) {
            int c = 64 * wv + mt * 16 + quad * 4 + r;
            float bi = b_out[c];
#pragma unroll
            for (int nt = 0; nt < 4; ++nt) {
                int tok = nt * 16 + l16;
                ob[((size_t)c * 128 + (tok >> 3)) * 128 + (tok & 7)] = pacc[mt][nt][r] + bi;
            }
        }
    }
}

extern "C" void kernel_launch(void* const* d_in, const int* in_sizes, int n_in,
                              void* d_out, int out_size, void* d_ws, size_t ws_size,
                              hipStream_t stream) {
    const float* x        = (const float*)d_in[0];
    const float* ln_gamma = (const float*)d_in[1];
    const float* ln_beta  = (const float*)d_in[2];
    const float* w_in     = (const float*)d_in[3];
    const float* b_in     = (const float*)d_in[4];
    const float* w_out    = (const float*)d_in[5];
    const float* b_out    = (const float*)d_in[6];
    float* y = (float*)d_out;

    _Float16* w_in_h  = (_Float16*)d_ws;            // 196608 halfs
    _Float16* w_out_h = w_in_h + 196608;            // 65536 halfs

    prep_weights_f16<<<1024, 256, 0, stream>>>(w_in, w_out, w_in_h);
    win_attn_fused<<<4096, 256, 0, stream>>>(x, ln_gamma, ln_beta, b_in, b_out,
                                             w_in_h, w_out_h, y);
}